// Round 6
// baseline (153.172 us; speedup 1.0000x reference)
//
#include <hip/hip_runtime.h>
#include <stdint.h>

#define BATCH 256
#define IDIM  8192
#define ODIM  8192
#define MS    64
#define IC    128
#define OC    128
#define NB    1024

#define TM 128
#define TN 128
#define KSPLIT 4
#define NIB (IC / KSPLIT)          // 32 rounds per workgroup

// LDS: A double-buffer ONLY, 2 x 8192 ushorts = 32 KB. B never touches LDS.
#define A_BASE(s) ((s) * 8192)

typedef __bf16 bf16x8 __attribute__((ext_vector_type(8)));
typedef float  floatx4 __attribute__((ext_vector_type(4)));

// s_waitcnt imm: vmcnt[3:0]|[15:14], expcnt/lgkmcnt = don't-care
#define WAITCNT_VM(n) ((((n) & 15) | (((n) >> 4) << 14)) | 0x70 | 0xF00)

__device__ __forceinline__ void async_load16(unsigned short* lds_p, const unsigned short* g_p) {
    __builtin_amdgcn_global_load_lds(
        (const __attribute__((address_space(1))) unsigned int*)g_p,
        (__attribute__((address_space(3))) unsigned int*)lds_p,
        16, 0, 0);
}

__device__ __forceinline__ unsigned short f32_to_bf16(float f) {
    unsigned int u = __float_as_uint(f);
    u += 0x7FFFu + ((u >> 16) & 1u);
    return (unsigned short)(u >> 16);
}

// ---- kernel 1: blocks -> bf16 [b][c][r] | x -> bf16 row-major | parts -> pT[ob][ib] ----
#define XCONV_BLKS 1024
#define PT_BLKS 64
__global__ void k_convert(const float* __restrict__ x, const float* __restrict__ blocks,
                          const int* __restrict__ parts,
                          unsigned short* __restrict__ xb, unsigned short* __restrict__ bt,
                          int* __restrict__ pT) {
    __shared__ float tile[MS][MS + 1];
    int b = blockIdx.x;
    if (b < NB) {
        const float4* src4 = (const float4*)(blocks + (size_t)b * MS * MS);
        unsigned short* dst = bt + (size_t)b * MS * MS;
        #pragma unroll
        for (int i = 0; i < 4; ++i) {
            int slot = i * 256 + threadIdx.x;
            int r = slot >> 4, c4 = (slot & 15) * 4;
            float4 v = src4[slot];
            tile[r][c4 + 0] = v.x; tile[r][c4 + 1] = v.y;
            tile[r][c4 + 2] = v.z; tile[r][c4 + 3] = v.w;
        }
        __syncthreads();
        #pragma unroll
        for (int i = 0; i < 2; ++i) {
            int slot = i * 256 + threadIdx.x;
            int c = slot >> 3, o = slot & 7;
            union { unsigned short s[8]; uint4 v; } u;
            #pragma unroll
            for (int j = 0; j < 8; ++j) u.s[j] = f32_to_bf16(tile[o * 8 + j][c]);
            *(uint4*)(dst + c * MS + o * 8) = u.v;        // bt[b][c][r] = [b][n][k]
        }
    } else if (b < NB + XCONV_BLKS) {
        int t = (b - NB) * 256 + threadIdx.x;
        const float4* x4 = (const float4*)x;
        float4 a = x4[2 * t], bb = x4[2 * t + 1];
        union { unsigned short s[8]; uint4 v; } u;
        u.s[0] = f32_to_bf16(a.x);  u.s[1] = f32_to_bf16(a.y);
        u.s[2] = f32_to_bf16(a.z);  u.s[3] = f32_to_bf16(a.w);
        u.s[4] = f32_to_bf16(bb.x); u.s[5] = f32_to_bf16(bb.y);
        u.s[6] = f32_to_bf16(bb.z); u.s[7] = f32_to_bf16(bb.w);
        ((uint4*)xb)[t] = u.v;
    } else {
        int t = (b - NB - XCONV_BLKS) * 256 + threadIdx.x;   // 16384
        int oc = t >> 7, ic = t & 127;
        pT[t] = parts[ic * OC + oc];                          // pT[ob][ib]
    }
}

// ---- kernel 2: GEMM 128x128, 4 waves (2x2, wave tile 64x64), 2 WG/CU.
//      EXACT round-0 proven structure (barriers, vmcnt flavor, A swizzle,
//      epilogue) with ONE change: B bypasses LDS. Each wave's 64-col band is
//      one 64x64 block; B frags load global->reg into two 4-frag banks:
//        round top : LOADB(b1, r, kk1)  then STAGE_A(r+1)
//        mid-round : LOADB(b0, r+1, kk0)
//      vm queue entering round r: [A(r)4, b0(r)4]; after top issues -> 16;
//      vmcnt(12) retires exactly A(r). Compiler-exact waits for b-banks:
//      b0 -> vmcnt(8), b1 -> vmcnt(8); never drains to 0 in steady state.
//      Per-round DS traffic halves (96KB -> 48KB per WG); B latency hides
//      behind the 2-WG/CU slip (the overlap mechanism round-0 validated).
extern __shared__ unsigned short smem[];   // 32 KB dynamic

__global__ __launch_bounds__(256, 2)
void k_mosaic_gemm(const unsigned short* __restrict__ xb,
                   const unsigned short* __restrict__ bt,
                   const int* __restrict__ pT,
                   float* __restrict__ partial) {
    const int tid  = threadIdx.x;
    const int lane = tid & 63;
    const int wave = tid >> 6;
    const int wrow = wave >> 1;      // 0..1 : 64-row band
    const int wcol = wave & 1;       // 0..1 : 64-col band == one module block
    const int nt = blockIdx.x;       // 0..63
    const int mt = blockIdx.y;       // 0..1
    const int ks = blockIdx.z;       // 0..3

    const int m0  = mt * TM;
    const int ob0 = nt * 2;
    const int ib0 = ks * NIB;

    const int row  = lane & 15;
    const int quad = lane >> 4;

    // preload all 32 rounds' part indices into lane registers (round = lane&31)
    int pv0 = pT[ob0 * IC + ib0 + (lane & 31)];
    int pv1 = pT[(ob0 + 1) * IC + ib0 + (lane & 31)];

    // iteration-invariant A ds_read element offsets (relative to stage base)
    // LDS XOR swizzle (verified 0 conflicts): LDS[r][oct] = global[r][oct^(r&7)]
    int a_off[2][4];
    #pragma unroll
    for (int kk = 0; kk < 2; ++kk) {
        int oct = kk * 4 + quad;
        #pragma unroll
        for (int mi = 0; mi < 4; ++mi) {
            int r = wrow * 64 + mi * 16 + row;
            a_off[kk][mi] = r * MS + ((oct ^ (r & 7)) << 3);
        }
    }

    floatx4 acc[4][4];
    #pragma unroll
    for (int mi = 0; mi < 4; ++mi)
        #pragma unroll
        for (int ni = 0; ni < 4; ++ni)
            acc[mi][ni] = (floatx4){0.f, 0.f, 0.f, 0.f};

    bf16x8 b0f[4], b1f[4];   // B register banks: kk0-half / kk1-half

    // 4 global_load_lds per thread per A-stage (16 KB) — vmcnt math relies on this
#define STAGE_A(abase, ibx) do {                                              \
    _Pragma("unroll")                                                         \
    for (int j = 0; j < 4; ++j) {                                             \
        int slot = j * 256 + tid;              /* 1024: 128 rows x 8 octets */ \
        int m = slot >> 3;                                                    \
        int oct = (slot & 7) ^ (m & 7);                                       \
        async_load16(smem + (abase) + slot * 8,                               \
                     xb + (size_t)(m0 + m) * IDIM + (ibx) * MS + oct * 8);    \
    } } while (0)

    // 4 global dwordx4 -> one B kk-half of this wave's block at ib = idx
    // layout verified r5: elem (n = ni*16+row, k-oct = quad + kkh*4)
#define LOADB(BB, idx, kkh) do {                                              \
    int sel = wcol ? pv1 : pv0;                                               \
    int q = __builtin_amdgcn_readfirstlane(__shfl(sel, (idx)));               \
    const char* bq = (const char*)(bt + (size_t)q * (MS * MS))                \
                     + row * 128 + quad * 16 + (kkh) * 64;                    \
    _Pragma("unroll")                                                         \
    for (int ni = 0; ni < 4; ++ni)                                            \
        BB[ni] = *(const bf16x8*)(bq + ni * 2048);                            \
    } while (0)

    // one kk-half: 4 A ds_reads + 16 MFMA against a B register bank
#define COMPUTE_K(acS, kk, BB) do {                                           \
    bf16x8 af[4];                                                             \
    _Pragma("unroll")                                                         \
    for (int mi = 0; mi < 4; ++mi)                                            \
        af[mi] = *(const bf16x8*)(smem + A_BASE(acS) + a_off[kk][mi]);        \
    _Pragma("unroll")                                                         \
    for (int mi = 0; mi < 4; ++mi)                                            \
        _Pragma("unroll")                                                     \
        for (int ni = 0; ni < 4; ++ni)                                        \
            acc[mi][ni] = __builtin_amdgcn_mfma_f32_16x16x32_bf16(            \
                af[mi], BB[ni], acc[mi][ni], 0, 0, 0);                        \
    } while (0)

    // one round; slot args literal at every call site (round-0 discipline)
#define ROUND(idx, acS, asS, STA, MIDB, WN) do {                              \
    LOADB(b1f, (idx), 1);                                                     \
    if (STA) STAGE_A(A_BASE(asS), ib0 + (idx) + 1);                           \
    __builtin_amdgcn_sched_barrier(0);                                        \
    __builtin_amdgcn_s_waitcnt(WAITCNT_VM(WN));                               \
    __builtin_amdgcn_s_barrier();                                             \
    __builtin_amdgcn_sched_barrier(0);                                        \
    COMPUTE_K(acS, 0, b0f);                                                   \
    if (MIDB) LOADB(b0f, (idx) + 1, 0);                                       \
    COMPUTE_K(acS, 1, b1f);                                                   \
    __builtin_amdgcn_sched_barrier(0);                                        \
    __builtin_amdgcn_s_barrier();                                             \
    __builtin_amdgcn_sched_barrier(0);                                        \
    } while (0)

    // prologue: queue = [A0x4, b0(0)x4] — matches steady-state round entry
    STAGE_A(A_BASE(0), ib0 + 0);
    LOADB(b0f, 0, 0);

    // steady rounds 0..29 (A slot r&1); 30,31 peeled for tail waits
    #pragma unroll 1
    for (int r2 = 0; r2 < 30; r2 += 2) {
        ROUND(r2,     0, 1, 1, 1, 12);
        ROUND(r2 + 1, 1, 0, 1, 1, 12);
    }
    ROUND(30, 0, 1, 1, 1, 12);   // stages A31->slot1, mid-loads b0(31)
    ROUND(31, 1, 0, 0, 0, 8);    // entering [A31,b0(31)]+b1(31)=12 -> vmcnt(8) retires A31

    // epilogue: C/D layout col = lane&15, row = quad*4 + reg (round-0 verified)
    float* out = partial + (size_t)ks * BATCH * ODIM;
    #pragma unroll
    for (int mi = 0; mi < 4; ++mi)
        #pragma unroll
        for (int ni = 0; ni < 4; ++ni)
            #pragma unroll
            for (int r = 0; r < 4; ++r) {
                int rowg = m0 + wrow * 64 + mi * 16 + quad * 4 + r;
                int colg = nt * TN + wcol * 64 + ni * 16 + row;
                out[(size_t)rowg * ODIM + colg] = acc[mi][ni][r];
            }
}

// ---- kernel 3: sum KSPLIT partials + bias ----
__global__ void k_reduce_bias(const float* __restrict__ partial,
                              const float* __restrict__ bias,
                              float* __restrict__ out) {
    int t = blockIdx.x * 256 + threadIdx.x;
    const float4* b4 = (const float4*)bias;
    float4 c = b4[t & (ODIM / 4 - 1)];
    float4 r = {c.x, c.y, c.z, c.w};
    #pragma unroll
    for (int k = 0; k < KSPLIT; ++k) {
        const float4* p = (const float4*)(partial + (size_t)k * BATCH * ODIM);
        float4 a = p[t];
        r.x += a.x; r.y += a.y; r.z += a.z; r.w += a.w;
    }
    ((float4*)out)[t] = r;
}

extern "C" void kernel_launch(void* const* d_in, const int* in_sizes, int n_in,
                              void* d_out, int out_size, void* d_ws, size_t ws_size,
                              hipStream_t stream) {
    const float* x      = (const float*)d_in[0];
    const float* blocks = (const float*)d_in[1];
    const float* bias   = (const float*)d_in[2];
    const int*   parts  = (const int*)d_in[3];
    float* out = (float*)d_out;

    char* ws = (char*)d_ws;
    unsigned short* xb      = (unsigned short*)ws;                      // 4 MB
    unsigned short* btb     = (unsigned short*)(ws + (4u << 20));       // 8 MB
    int*            pTr     = (int*)(ws + (12u << 20));                 // 64 KB
    float*          partial = (float*)(ws + (13u << 20));               // 32 MB

    static bool attr_set = false;
    if (!attr_set) {
        hipFuncSetAttribute((const void*)k_mosaic_gemm,
                            hipFuncAttributeMaxDynamicSharedMemorySize, 32 * 1024);
        attr_set = true;
    }

    k_convert<<<NB + XCONV_BLKS + PT_BLKS, 256, 0, stream>>>(x, blocks, parts, xb, btb, pTr);
    k_mosaic_gemm<<<dim3(ODIM / TN, BATCH / TM, KSPLIT), 256, 32 * 1024, stream>>>(xb, btb, pTr, partial);
    k_reduce_bias<<<(BATCH * ODIM) / (256 * 4), 256, 0, stream>>>(partial, bias, out);
}

// Round 7
// 128.752 us; speedup vs baseline: 1.1897x; 1.1897x over previous
//
#include <hip/hip_runtime.h>
#include <stdint.h>

#define BATCH 256
#define IDIM  8192
#define ODIM  8192
#define MS    64
#define IC    128
#define OC    128
#define NB    1024

#define TM 128
#define TN 128
#define KSPLIT 4
#define NIB (IC / KSPLIT)          // 32 rounds per workgroup

// dynamic LDS layout (ushort offsets): A dbuf 2 x 8192, B ring-3 3 x 8192 = 80 KB
#define A_BASE(s) ((s) * 8192)
#define B_BASE(s) (16384 + (s) * 8192)

typedef __bf16 bf16x8 __attribute__((ext_vector_type(8)));
typedef float  floatx4 __attribute__((ext_vector_type(4)));

// s_waitcnt imm: vmcnt[3:0]|[15:14], expcnt/lgkmcnt = don't-care
#define WAITCNT_VM(n) ((((n) & 15) | (((n) >> 4) << 14)) | 0x70 | 0xF00)

__device__ __forceinline__ void async_load16(unsigned short* lds_p, const unsigned short* g_p) {
    __builtin_amdgcn_global_load_lds(
        (const __attribute__((address_space(1))) unsigned int*)g_p,
        (__attribute__((address_space(3))) unsigned int*)lds_p,
        16, 0, 0);
}

__device__ __forceinline__ unsigned short f32_to_bf16(float f) {
    unsigned int u = __float_as_uint(f);
    u += 0x7FFFu + ((u >> 16) & 1u);
    return (unsigned short)(u >> 16);
}

// ---- kernel 1: blocks -> bf16 [b][c][r] | x -> bf16 | parts -> pT | out <- bias ----
#define XCONV_BLKS 1024
#define PT_BLKS 64
#define BIAS_BLKS 2048
__global__ void k_convert(const float* __restrict__ x, const float* __restrict__ blocks,
                          const int* __restrict__ parts, const float* __restrict__ bias,
                          unsigned short* __restrict__ xb, unsigned short* __restrict__ bt,
                          int* __restrict__ pT, float* __restrict__ out) {
    __shared__ float tile[MS][MS + 1];
    int b = blockIdx.x;
    if (b < NB) {
        const float4* src4 = (const float4*)(blocks + (size_t)b * MS * MS);
        unsigned short* dst = bt + (size_t)b * MS * MS;
        #pragma unroll
        for (int i = 0; i < 4; ++i) {
            int slot = i * 256 + threadIdx.x;
            int r = slot >> 4, c4 = (slot & 15) * 4;
            float4 v = src4[slot];
            tile[r][c4 + 0] = v.x; tile[r][c4 + 1] = v.y;
            tile[r][c4 + 2] = v.z; tile[r][c4 + 3] = v.w;
        }
        __syncthreads();
        #pragma unroll
        for (int i = 0; i < 2; ++i) {
            int slot = i * 256 + threadIdx.x;
            int c = slot >> 3, o = slot & 7;
            union { unsigned short s[8]; uint4 v; } u;
            #pragma unroll
            for (int j = 0; j < 8; ++j) u.s[j] = f32_to_bf16(tile[o * 8 + j][c]);
            *(uint4*)(dst + c * MS + o * 8) = u.v;        // bt[b][c][r]
        }
    } else if (b < NB + XCONV_BLKS) {
        int t = (b - NB) * 256 + threadIdx.x;
        const float4* x4 = (const float4*)x;
        float4 a = x4[2 * t], bb = x4[2 * t + 1];
        union { unsigned short s[8]; uint4 v; } u;
        u.s[0] = f32_to_bf16(a.x);  u.s[1] = f32_to_bf16(a.y);
        u.s[2] = f32_to_bf16(a.z);  u.s[3] = f32_to_bf16(a.w);
        u.s[4] = f32_to_bf16(bb.x); u.s[5] = f32_to_bf16(bb.y);
        u.s[6] = f32_to_bf16(bb.z); u.s[7] = f32_to_bf16(bb.w);
        ((uint4*)xb)[t] = u.v;
    } else if (b < NB + XCONV_BLKS + PT_BLKS) {
        int t = (b - NB - XCONV_BLKS) * 256 + threadIdx.x;   // 16384
        int oc = t >> 7, ic = t & 127;
        pT[t] = parts[ic * OC + oc];                          // pT[ob][ib]
    } else {
        // bias-broadcast init of out [256][8192]; gemm atomically accumulates
        int t = (b - NB - XCONV_BLKS - PT_BLKS) * 256 + threadIdx.x;  // 0..524287
        const float4* b4 = (const float4*)bias;
        ((float4*)out)[t] = b4[t & (ODIM / 4 - 1)];
    }
}

// ---- kernel 2: GEMM 128x128 — VERBATIM round-0 proven structure (42.4 us):
//      A dbuf(depth-1) + B ring-3(depth-2), 2 wg/CU, compile-time slots
//      (6-round unroll), sched_barrier-pinned region order.
//      Round i: stage A_{i+1}->slot (i+1)&1, B_{i+2}->slot (i+2)%3; wait
//      vmcnt(12) retires exactly A_i,B_i; compute A slot i&1, B slot i%3.
//      LDS XOR swizzle (verified 0 conflicts): LDS[r][oct] = global[r][oct^(r&7)]
//      ONLY change vs round-0: epilogue stores -> global atomicAdd into out
//      (bias pre-initialized by k_convert), eliminating partial+reduce kernel.
extern __shared__ unsigned short smem[];   // 80 KB dynamic

__global__ __launch_bounds__(256, 2)
void k_mosaic_gemm(const unsigned short* __restrict__ xb,
                   const unsigned short* __restrict__ bt,
                   const int* __restrict__ pT,
                   float* __restrict__ out) {
    const int tid  = threadIdx.x;
    const int lane = tid & 63;
    const int wave = tid >> 6;
    const int wrow = wave >> 1;      // 0..1 : 64-row band
    const int wcol = wave & 1;       // 0..1 : 64-col band
    const int nt = blockIdx.x;       // 0..63
    const int mt = blockIdx.y;       // 0..1
    const int ks = blockIdx.z;       // 0..3

    const int m0  = mt * TM;
    const int ob0 = nt * 2;
    const int ib0 = ks * NIB;

    const int row  = lane & 15;
    const int quad = lane >> 4;

    // preload all 32 rounds' part indices into lane registers
    int pv0 = pT[ob0 * IC + ib0 + (lane & 31)];
    int pv1 = pT[(ob0 + 1) * IC + ib0 + (lane & 31)];

    // iteration-invariant ds_read element offsets (relative to stage base)
    int a_off[2][4], b_off[2][4];
    #pragma unroll
    for (int kk = 0; kk < 2; ++kk) {
        int oct = kk * 4 + quad;
        #pragma unroll
        for (int mi = 0; mi < 4; ++mi) {
            int r = wrow * 64 + mi * 16 + row;
            a_off[kk][mi] = r * MS + ((oct ^ (r & 7)) << 3);
        }
        #pragma unroll
        for (int ni = 0; ni < 4; ++ni) {
            int n = wcol * 64 + ni * 16 + row;
            b_off[kk][ni] = n * MS + ((oct ^ (n & 7)) << 3);
        }
    }

    floatx4 acc[4][4];
    #pragma unroll
    for (int mi = 0; mi < 4; ++mi)
        #pragma unroll
        for (int ni = 0; ni < 4; ++ni)
            acc[mi][ni] = (floatx4){0.f, 0.f, 0.f, 0.f};

    // 4 global_load_lds per thread per A-stage / per B-stage — vmcnt math relies on this
#define STAGE_A(abase, ibx) do {                                              \
    _Pragma("unroll")                                                         \
    for (int j = 0; j < 4; ++j) {                                             \
        int slot = j * 256 + tid;              /* 1024: 128 rows x 8 octets */ \
        int m = slot >> 3;                                                    \
        int oct = (slot & 7) ^ (m & 7);                                       \
        async_load16(smem + (abase) + slot * 8,                               \
                     xb + (size_t)(m0 + m) * IDIM + (ibx) * MS + oct * 8);    \
    } } while (0)

#define STAGE_B(bbase, pa, pb) do {                                           \
    _Pragma("unroll")                                                         \
    for (int j = 0; j < 4; ++j) {                                             \
        int slot = j * 256 + tid;              /* 1024: 128 rows x 8 octets */ \
        int n = slot >> 3;                                                    \
        int oct = (slot & 7) ^ (n & 7);                                       \
        int p = (j < 2) ? (pa) : (pb);                                        \
        async_load16(smem + (bbase) + slot * 8,                               \
                     bt + (size_t)p * (MS * MS) + (n & 63) * MS + oct * 8);   \
    } } while (0)

#define COMPUTE(abase, bbase) do {                                            \
    _Pragma("unroll")                                                         \
    for (int kk = 0; kk < 2; ++kk) {                                          \
        bf16x8 af[4], bfr[4];                                                 \
        _Pragma("unroll")                                                     \
        for (int mi = 0; mi < 4; ++mi)                                        \
            af[mi] = *(const bf16x8*)(smem + (abase) + a_off[kk][mi]);        \
        _Pragma("unroll")                                                     \
        for (int ni = 0; ni < 4; ++ni)                                        \
            bfr[ni] = *(const bf16x8*)(smem + (bbase) + b_off[kk][ni]);       \
        _Pragma("unroll")                                                     \
        for (int mi = 0; mi < 4; ++mi)                                        \
            _Pragma("unroll")                                                 \
            for (int ni = 0; ni < 4; ++ni)                                    \
                acc[mi][ni] = __builtin_amdgcn_mfma_f32_16x16x32_bf16(        \
                    af[mi], bfr[ni], acc[mi][ni], 0, 0, 0);                   \
    } } while (0)

    // one fully-pinned round; slot args are LITERAL constants at every call site
#define ROUND(idx, acS, bcS, asS, bsS) do {                                   \
    STAGE_A(A_BASE(asS), ib0 + (idx) + 1);                                    \
    { int q0 = __shfl(pv0, (idx) + 2), q1 = __shfl(pv1, (idx) + 2);           \
      STAGE_B(B_BASE(bsS), q0, q1); }                                         \
    __builtin_amdgcn_sched_barrier(0);                                        \
    __builtin_amdgcn_s_waitcnt(WAITCNT_VM(12));                               \
    __builtin_amdgcn_s_barrier();                                             \
    __builtin_amdgcn_sched_barrier(0);                                        \
    COMPUTE(A_BASE(acS), B_BASE(bcS));                                        \
    __builtin_amdgcn_sched_barrier(0);                                        \
    __builtin_amdgcn_s_barrier();                                             \
    __builtin_amdgcn_sched_barrier(0);                                        \
    } while (0)

    // prologue: queue = [A0, B0, B1]  (12 ops in flight)
    STAGE_A(A_BASE(0), ib0 + 0);
    { int q0 = __shfl(pv0, 0), q1 = __shfl(pv1, 0); STAGE_B(B_BASE(0), q0, q1); }
    { int q0 = __shfl(pv0, 1), q1 = __shfl(pv1, 1); STAGE_B(B_BASE(1), q0, q1); }

    // steady rounds 0..29: 5 x 6-round unroll; (i6 even, i6 % 3 == 0) keeps slot
    // patterns exact: compute A slot r&1 / B slot r%3, stage A (r+1)&1 / B (r+2)%3
    for (int i6 = 0; i6 < 30; i6 += 6) {
        ROUND(i6 + 0, 0, 0, 1, 2);
        ROUND(i6 + 1, 1, 1, 0, 0);
        ROUND(i6 + 2, 0, 2, 1, 1);
        ROUND(i6 + 3, 1, 0, 0, 2);
        ROUND(i6 + 4, 0, 1, 1, 0);
        ROUND(i6 + 5, 1, 2, 0, 1);
    }
    // round 30: stage A31 -> slot 1; retire B30,A30 (8 younger: B31,A31); compute A@0,B@0
    STAGE_A(A_BASE(1), ib0 + NIB - 1);
    __builtin_amdgcn_sched_barrier(0);
    __builtin_amdgcn_s_waitcnt(WAITCNT_VM(8));
    __builtin_amdgcn_s_barrier();
    __builtin_amdgcn_sched_barrier(0);
    COMPUTE(A_BASE(0), B_BASE(0));
    __builtin_amdgcn_sched_barrier(0);
    __builtin_amdgcn_s_barrier();
    __builtin_amdgcn_sched_barrier(0);
    // round 31: retire everything; compute A@1,B@1
    __builtin_amdgcn_s_waitcnt(WAITCNT_VM(0));
    __builtin_amdgcn_s_barrier();
    __builtin_amdgcn_sched_barrier(0);
    COMPUTE(A_BASE(1), B_BASE(1));

    // epilogue: C/D layout col = lane&15, row = quad*4 + reg.
    // atomicAdd into bias-initialized out (device-scope; replaces partial+reduce)
    #pragma unroll
    for (int mi = 0; mi < 4; ++mi)
        #pragma unroll
        for (int ni = 0; ni < 4; ++ni)
            #pragma unroll
            for (int r = 0; r < 4; ++r) {
                int rowg = m0 + wrow * 64 + mi * 16 + quad * 4 + r;
                int colg = nt * TN + wcol * 64 + ni * 16 + row;
                atomicAdd(&out[(size_t)rowg * ODIM + colg], acc[mi][ni][r]);
            }
}

extern "C" void kernel_launch(void* const* d_in, const int* in_sizes, int n_in,
                              void* d_out, int out_size, void* d_ws, size_t ws_size,
                              hipStream_t stream) {
    const float* x      = (const float*)d_in[0];
    const float* blocks = (const float*)d_in[1];
    const float* bias   = (const float*)d_in[2];
    const int*   parts  = (const int*)d_in[3];
    float* out = (float*)d_out;

    char* ws = (char*)d_ws;
    unsigned short* xb  = (unsigned short*)ws;                      // 4 MB
    unsigned short* btb = (unsigned short*)(ws + (4u << 20));       // 8 MB
    int*            pTr = (int*)(ws + (12u << 20));                 // 64 KB

    // allow 80 KB dynamic LDS (idempotent; host-side, graph-capture safe)
    static bool attr_set = false;
    if (!attr_set) {
        hipFuncSetAttribute((const void*)k_mosaic_gemm,
                            hipFuncAttributeMaxDynamicSharedMemorySize, 80 * 1024);
        attr_set = true;
    }

    k_convert<<<NB + XCONV_BLKS + PT_BLKS + BIAS_BLKS, 256, 0, stream>>>(
        x, blocks, parts, bias, xb, btb, pTr, out);
    k_mosaic_gemm<<<dim3(ODIM / TN, BATCH / TM, KSPLIT), 256, 80 * 1024, stream>>>(
        xb, btb, pTr, out);
}